// Round 10
// baseline (254.839 us; speedup 1.0000x reference)
//
#include <hip/hip_runtime.h>

// NTXentLoss, B=8192, D=128, T=0.1, idx=0. fp32 in, fp32 scalar out.
// R16: row-owner fusion. Budget evidence: R4-vs-R7 shows the separate
// posfinal DISPATCH costs ~23 us of stream time; R10 proved fusion works
// but died of per-block agent fences. Fix: 256 blocks x 1024 thr; block
// owns 32 rows end-to-end (denom never leaves the block -> no cross-block
// dependency, no fences). Each of 16 waves streams its own 512 cols via a
// PRIVATE 8 KB LDS slice (2 x 4KB chunk dbuf, global_load_lds, counted
// vmcnt(4)) -> producer==consumer==wave: ZERO in-loop barriers (m233
// convoy killer, kept from R13-15) + LDS bandwidth (fixes R12's exposed
// L2 latency). Labels pre-staged to LDS u16 (no vmcnt pollution). Per-wave
// rs -> ds_add_f32 rowsum -> 1 syncthreads -> in-block posfinal (verbatim
// math) -> 1 atomicAdd(out). LDS 147.6 KB (1 blk/CU, 4 waves/SIMD).

#define BB 8192
#define DD 128
#define RPB 32           // rows per block
#define CPW 512          // cols per wave
#define NCH 32           // 16-col chunks per wave

typedef __attribute__((ext_vector_type(8))) short short8;
typedef __attribute__((ext_vector_type(4))) float floatx4;

#define GLOBAL_AS __attribute__((address_space(1)))
#define LDS_AS    __attribute__((address_space(3)))

#define L2E10 14.4269504088896340f   // 10 * log2(e)

static __device__ __forceinline__ float wave_sum(float v) {
#pragma unroll
    for (int off = 32; off > 0; off >>= 1) v += __shfl_xor(v, off, 64);
    return v;
}

static __device__ __forceinline__ unsigned short f2bf(float f) {
    unsigned int u = __float_as_uint(f);
    return (unsigned short)((u + 0x7FFFu + ((u >> 16) & 1u)) >> 16);
}

// ---- prep: normalize rows -> bf16 + 1/norm; zero out ---------------------
__global__ __launch_bounds__(256) void prep_kernel(
    const float* __restrict__ zis, const float* __restrict__ zjs,
    unsigned short* __restrict__ Zib, unsigned short* __restrict__ Zjb,
    float* __restrict__ rni, float* __restrict__ rnj,
    float* __restrict__ out, int nout)
{
    if (blockIdx.x == 0 && (int)threadIdx.x < nout) out[threadIdx.x] = 0.0f;

    int wave = threadIdx.x >> 6, lane = threadIdx.x & 63;
    int row = blockIdx.x * 4 + wave;
    const float* src; unsigned short* dst; float* rn; int r;
    if (row < BB) { src = zis; dst = Zib; rn = rni; r = row; }
    else          { src = zjs; dst = Zjb; rn = rnj; r = row - BB; }
    float2 u = *(const float2*)(src + (size_t)r * DD + lane * 2);
    float s = wave_sum(u.x * u.x + u.y * u.y);
    float sc = 1.0f / sqrtf(s);
    if (lane == 0) rn[r] = sc;
    ushort2 o; o.x = f2bf(u.x * sc); o.y = f2bf(u.y * sc);
    *(ushort2*)(dst + (size_t)r * DD + lane * 2) = o;
}

// ---- fused row-owner kernel ----------------------------------------------
// Wave slice: 2 chunk buffers of 4 KB (16 cols x 256 B). Staging (rule #21):
// load u, lane l -> col u*4+(l>>4), source slot s = (l&15)^(u*4+(l>>4)),
// dest linear (lane*16). Read col l15, slot sl=ks*4+quad at (sl^l15)*16 --
// exact scheme measured 0 bank conflicts in R13.
__global__ __launch_bounds__(1024, 4) void fused_kernel(
    const unsigned short* __restrict__ Zjb,   // A: zj normalized (rows i)
    const unsigned short* __restrict__ Zib,   // B: zi normalized (cols j)
    const int* __restrict__ ilab, const int* __restrict__ jlab,
    const float* __restrict__ zis, const float* __restrict__ zjs,
    const float* __restrict__ rni, const float* __restrict__ rnj,
    const float* __restrict__ wts, const int* __restrict__ idxp,
    float* __restrict__ out)
{
    __shared__ __align__(16) unsigned short Bp[16 * 4096];   // 128 KB
    __shared__ unsigned short Il2[BB];                       // 16 KB
    __shared__ float rowsum[RPB];
    __shared__ float part[16];

    int tid  = threadIdx.x;
    int lane = tid & 63, wave = tid >> 6;     // 16 waves
    int quad = lane >> 4, l15 = lane & 15;
    int r0  = blockIdx.x * RPB;
    int cw0 = wave * CPW;

    // all 8192 i-labels -> LDS u16 (labels < 100); rowsum init
#pragma unroll
    for (int k = 0; k < BB / 1024; ++k)
        Il2[k * 1024 + tid] = (unsigned short)ilab[k * 1024 + tid];
    if (tid < RPB) rowsum[tid] = 0.0f;
    __syncthreads();                          // drains all the above

    // A fragments (32 VGPR): row r0+mt*16+l15, k = ks*32+quad*8
    short8 af[2][4];
#pragma unroll
    for (int mt = 0; mt < 2; ++mt)
#pragma unroll
        for (int ks = 0; ks < 4; ++ks)
            af[mt][ks] = *(const short8*)(Zjb
                + (size_t)(r0 + mt * 16 + l15) * DD + ks * 32 + quad * 8);

    int jrv[8];
#pragma unroll
    for (int mt = 0; mt < 2; ++mt)
#pragma unroll
        for (int r = 0; r < 4; ++r)
            jrv[mt * 4 + r] = jlab[r0 + mt * 16 + quad * 4 + r];

    // LDS read bases (swizzled, granule-invariant); parity adds 2048 ushorts
    unsigned short* wsl = &Bp[wave * 4096];
    const unsigned short* rb0 = wsl + l15 * 128 + (((0 + quad) ^ l15) * 8);
    const unsigned short* rb1 = wsl + l15 * 128 + (((4 + quad) ^ l15) * 8);
    const unsigned short* rb2 = wsl + l15 * 128 + (((8 + quad) ^ l15) * 8);
    const unsigned short* rb3 = wsl + l15 * 128 + (((12 + quad) ^ l15) * 8);

    // global stage sources (per-lane, inverse-swizzled); chunk g adds g*2048
    const unsigned short* g0 = Zib + (size_t)(cw0 + 0 + quad) * DD + ((l15 ^ (0 + quad)) * 8);
    const unsigned short* g1 = Zib + (size_t)(cw0 + 4 + quad) * DD + ((l15 ^ (4 + quad)) * 8);
    const unsigned short* g2 = Zib + (size_t)(cw0 + 8 + quad) * DD + ((l15 ^ (8 + quad)) * 8);
    const unsigned short* g3 = Zib + (size_t)(cw0 + 12 + quad) * DD + ((l15 ^ (12 + quad)) * 8);

#define STG(g) do {                                                         \
        unsigned short* lb = wsl + ((g) & 1) * 2048;                        \
        __builtin_amdgcn_global_load_lds((const GLOBAL_AS void*)(g0 + (g) * 2048), \
                                         (LDS_AS void*)(lb + 0 * 512), 16, 0, 0);  \
        __builtin_amdgcn_global_load_lds((const GLOBAL_AS void*)(g1 + (g) * 2048), \
                                         (LDS_AS void*)(lb + 1 * 512), 16, 0, 0);  \
        __builtin_amdgcn_global_load_lds((const GLOBAL_AS void*)(g2 + (g) * 2048), \
                                         (LDS_AS void*)(lb + 2 * 512), 16, 0, 0);  \
        __builtin_amdgcn_global_load_lds((const GLOBAL_AS void*)(g3 + (g) * 2048), \
                                         (LDS_AS void*)(lb + 3 * 512), 16, 0, 0);  \
    } while (0)

    float rs[2][4];
#pragma unroll
    for (int mt = 0; mt < 2; ++mt)
#pragma unroll
        for (int r = 0; r < 4; ++r) rs[mt][r] = 0.0f;

    STG(0);
    STG(1);

    __builtin_amdgcn_s_setprio(1);
#pragma unroll
    for (int g = 0; g < NCH; ++g) {
        // chunk g retired when everything newer than window g (4 ops of
        // chunk g+1) may remain: vmcnt(4); last chunk: drain.
        if (g < NCH - 1) asm volatile("s_waitcnt vmcnt(4)" ::: "memory");
        else             asm volatile("s_waitcnt vmcnt(0)" ::: "memory");
        const int P = (g & 1) * 2048;
        short8 b0 = *(const short8*)(rb0 + P);
        short8 b1 = *(const short8*)(rb1 + P);
        short8 b2 = *(const short8*)(rb2 + P);
        short8 b3 = *(const short8*)(rb3 + P);
        int ilg = (int)Il2[cw0 + g * 16 + l15];
        // capture b in regs before same-buffer overwrite (LDS write of
        // STG(g+2) lands via the TA->LDS path, unordered vs ds_read issue)
        asm volatile("s_waitcnt lgkmcnt(0)" ::: "memory");
        if (g + 2 < NCH) STG(g + 2);

        floatx4 zz = (floatx4){0.f, 0.f, 0.f, 0.f};
        floatx4 acc0, acc1;
        acc0 = __builtin_amdgcn_mfma_f32_16x16x32_bf16(af[0][0], b0, zz, 0, 0, 0);
        acc1 = __builtin_amdgcn_mfma_f32_16x16x32_bf16(af[1][0], b0, zz, 0, 0, 0);
        acc0 = __builtin_amdgcn_mfma_f32_16x16x32_bf16(af[0][1], b1, acc0, 0, 0, 0);
        acc1 = __builtin_amdgcn_mfma_f32_16x16x32_bf16(af[1][1], b1, acc1, 0, 0, 0);
        acc0 = __builtin_amdgcn_mfma_f32_16x16x32_bf16(af[0][2], b2, acc0, 0, 0, 0);
        acc1 = __builtin_amdgcn_mfma_f32_16x16x32_bf16(af[1][2], b2, acc1, 0, 0, 0);
        acc0 = __builtin_amdgcn_mfma_f32_16x16x32_bf16(af[0][3], b3, acc0, 0, 0, 0);
        acc1 = __builtin_amdgcn_mfma_f32_16x16x32_bf16(af[1][3], b3, acc1, 0, 0, 0);

        // EPI: e = exp(10c-10) via exp2; mask; accumulate
#pragma unroll
        for (int r = 0; r < 4; ++r) {
            float e0 = __builtin_amdgcn_exp2f(fmaf(acc0[r], L2E10, -L2E10));
            rs[0][r] += (ilg != jrv[r]) ? e0 : 0.0f;
            float e1 = __builtin_amdgcn_exp2f(fmaf(acc1[r], L2E10, -L2E10));
            rs[1][r] += (ilg != jrv[4 + r]) ? e1 : 0.0f;
        }
    }
    __builtin_amdgcn_s_setprio(0);
#undef STG

    // ---- combine: l15-reduce then LDS-atomic rowsum ----------------------
#pragma unroll
    for (int mt = 0; mt < 2; ++mt)
#pragma unroll
        for (int r = 0; r < 4; ++r) {
            float v = rs[mt][r];
            v += __shfl_xor(v, 1, 64);
            v += __shfl_xor(v, 2, 64);
            v += __shfl_xor(v, 4, 64);
            v += __shfl_xor(v, 8, 64);
            if (l15 == 0)
                atomicAdd(&rowsum[mt * 16 + quad * 4 + r], v);
        }
    __syncthreads();                          // all waves' denoms in rowsum

    // ---- in-block posfinal (verbatim math), 2 rows per wave --------------
    int idx2 = idxp[0];
    float ll = 0.0f;
#pragma unroll
    for (int t = 0; t < 2; ++t) {
        int irl = wave * 2 + t;
        int i = r0 + irl;
        int j = idx2 + i;
        float2 a  = *(const float2*)(zjs + (size_t)i * DD + lane * 2);
        float2 b2 = *(const float2*)(zis + (size_t)j * DD + lane * 2);
        float s = wave_sum(a.x * b2.x + a.y * b2.y);
        if (lane == 0) {
            float p = s * rni[j] * rnj[i] * 10.0f;
            float l = 10.0f + logf(__expf(p - 10.0f) + rowsum[irl]) - p;
            float w = wts[j];
            ll += (l * w) / w;    // faithful to reference's weighted mean
        }
    }
    if (lane == 0) part[wave] = ll;
    __syncthreads();
    if (tid == 0) {
        float sum = 0.0f;
#pragma unroll
        for (int q = 0; q < 16; ++q) sum += part[q];
        atomicAdd(out, sum * (1.0f / BB));
    }
}

// ---- launch --------------------------------------------------------------
extern "C" void kernel_launch(void* const* d_in, const int* in_sizes, int n_in,
                              void* d_out, int out_size, void* d_ws, size_t ws_size,
                              hipStream_t stream) {
    const float* zis = (const float*)d_in[0];
    const float* zjs = (const float*)d_in[1];
    const int* ilab = (const int*)d_in[2];
    const int* jlab = (const int*)d_in[3];
    const float* wts = (const float*)d_in[4];
    const int* idxp = (const int*)d_in[5];
    float* out = (float*)d_out;

    float* rni   = (float*)d_ws;
    float* rnj   = rni + BB;
    unsigned short* Zib = (unsigned short*)(rnj + BB);    // [BB][DD] bf16
    unsigned short* Zjb = Zib + (size_t)BB * DD;

    prep_kernel<<<2 * BB / 4, 256, 0, stream>>>(
        zis, zjs, Zib, Zjb, rni, rnj, out, out_size);
    fused_kernel<<<BB / RPB, 1024, 0, stream>>>(
        Zjb, Zib, ilab, jlab, zis, zjs, rni, rnj, wts, idxp, out);
}

// Round 12
// 250.563 us; speedup vs baseline: 1.0171x; 1.0171x over previous
//
#include <hip/hip_runtime.h>

// NTXentLoss, B=8192, D=128, T=0.1, idx=0. fp32 in, fp32 scalar out.
// R18 == R17 resubmitted (R17 bench was an infra failure: "MI355X container
// failed twice"; no counters produced, nothing to learn -> rerun, don't
// mutate). R16's 174us was the third VGPR-cap spill: __launch_bounds__
// 2nd arg acts as min-BLOCKS-per-CU (pinned by R8/R9/R13/R16): (1024,4) =
// 64 waves/CU -> 64-VGPR cap vs ~105 live -> 223 MB scratch writes, L2
// thrash (FETCH 270 MB). Now (1024,1): 1 block/CU (all that 148 KB LDS
// fits anyway), 16 waves = 4/SIMD, 128-VGPR cap -> no spill. Structure
// unchanged from R16 (absmax 0 verified): row-owner fusion, block owns 32
// rows end-to-end, wave-private 8 KB dbuf staging w/ counted vmcnt(4),
// ZERO in-loop barriers, no fences, in-block posfinal, 1 atomic/block.

#define BB 8192
#define DD 128
#define RPB 32           // rows per block
#define CPW 512          // cols per wave
#define NCH 32           // 16-col chunks per wave

typedef __attribute__((ext_vector_type(8))) short short8;
typedef __attribute__((ext_vector_type(4))) float floatx4;

#define GLOBAL_AS __attribute__((address_space(1)))
#define LDS_AS    __attribute__((address_space(3)))

#define L2E10 14.4269504088896340f   // 10 * log2(e)

static __device__ __forceinline__ float wave_sum(float v) {
#pragma unroll
    for (int off = 32; off > 0; off >>= 1) v += __shfl_xor(v, off, 64);
    return v;
}

static __device__ __forceinline__ unsigned short f2bf(float f) {
    unsigned int u = __float_as_uint(f);
    return (unsigned short)((u + 0x7FFFu + ((u >> 16) & 1u)) >> 16);
}

// ---- prep: normalize rows -> bf16 + 1/norm; zero out ---------------------
__global__ __launch_bounds__(256) void prep_kernel(
    const float* __restrict__ zis, const float* __restrict__ zjs,
    unsigned short* __restrict__ Zib, unsigned short* __restrict__ Zjb,
    float* __restrict__ rni, float* __restrict__ rnj,
    float* __restrict__ out, int nout)
{
    if (blockIdx.x == 0 && (int)threadIdx.x < nout) out[threadIdx.x] = 0.0f;

    int wave = threadIdx.x >> 6, lane = threadIdx.x & 63;
    int row = blockIdx.x * 4 + wave;
    const float* src; unsigned short* dst; float* rn; int r;
    if (row < BB) { src = zis; dst = Zib; rn = rni; r = row; }
    else          { src = zjs; dst = Zjb; rn = rnj; r = row - BB; }
    float2 u = *(const float2*)(src + (size_t)r * DD + lane * 2);
    float s = wave_sum(u.x * u.x + u.y * u.y);
    float sc = 1.0f / sqrtf(s);
    if (lane == 0) rn[r] = sc;
    ushort2 o; o.x = f2bf(u.x * sc); o.y = f2bf(u.y * sc);
    *(ushort2*)(dst + (size_t)r * DD + lane * 2) = o;
}

// ---- fused row-owner kernel ----------------------------------------------
// Wave slice: 2 chunk buffers of 4 KB (16 cols x 256 B). Staging (rule #21):
// load u, lane l -> col u*4+(l>>4), source slot s = (l&15)^(u*4+(l>>4)),
// dest linear (lane*16). Read col l15, slot sl=ks*4+quad at (sl^l15)*16 --
// exact scheme measured 0 bank conflicts in R13.
__global__ __launch_bounds__(1024, 1) void fused_kernel(
    const unsigned short* __restrict__ Zjb,   // A: zj normalized (rows i)
    const unsigned short* __restrict__ Zib,   // B: zi normalized (cols j)
    const int* __restrict__ ilab, const int* __restrict__ jlab,
    const float* __restrict__ zis, const float* __restrict__ zjs,
    const float* __restrict__ rni, const float* __restrict__ rnj,
    const float* __restrict__ wts, const int* __restrict__ idxp,
    float* __restrict__ out)
{
    __shared__ __align__(16) unsigned short Bp[16 * 4096];   // 128 KB
    __shared__ unsigned short Il2[BB];                       // 16 KB
    __shared__ float rowsum[RPB];
    __shared__ float part[16];

    int tid  = threadIdx.x;
    int lane = tid & 63, wave = tid >> 6;     // 16 waves
    int quad = lane >> 4, l15 = lane & 15;
    int r0  = blockIdx.x * RPB;
    int cw0 = wave * CPW;

    // all 8192 i-labels -> LDS u16 (labels < 100); rowsum init
#pragma unroll
    for (int k = 0; k < BB / 1024; ++k)
        Il2[k * 1024 + tid] = (unsigned short)ilab[k * 1024 + tid];
    if (tid < RPB) rowsum[tid] = 0.0f;
    __syncthreads();                          // drains all the above

    // A fragments (32 VGPR): row r0+mt*16+l15, k = ks*32+quad*8
    short8 af[2][4];
#pragma unroll
    for (int mt = 0; mt < 2; ++mt)
#pragma unroll
        for (int ks = 0; ks < 4; ++ks)
            af[mt][ks] = *(const short8*)(Zjb
                + (size_t)(r0 + mt * 16 + l15) * DD + ks * 32 + quad * 8);

    int jrv[8];
#pragma unroll
    for (int mt = 0; mt < 2; ++mt)
#pragma unroll
        for (int r = 0; r < 4; ++r)
            jrv[mt * 4 + r] = jlab[r0 + mt * 16 + quad * 4 + r];

    // LDS read bases (swizzled, granule-invariant); parity adds 2048 ushorts
    unsigned short* wsl = &Bp[wave * 4096];
    const unsigned short* rb0 = wsl + l15 * 128 + (((0 + quad) ^ l15) * 8);
    const unsigned short* rb1 = wsl + l15 * 128 + (((4 + quad) ^ l15) * 8);
    const unsigned short* rb2 = wsl + l15 * 128 + (((8 + quad) ^ l15) * 8);
    const unsigned short* rb3 = wsl + l15 * 128 + (((12 + quad) ^ l15) * 8);

    // global stage sources (per-lane, inverse-swizzled); chunk g adds g*2048
    const unsigned short* g0 = Zib + (size_t)(cw0 + 0 + quad) * DD + ((l15 ^ (0 + quad)) * 8);
    const unsigned short* g1 = Zib + (size_t)(cw0 + 4 + quad) * DD + ((l15 ^ (4 + quad)) * 8);
    const unsigned short* g2 = Zib + (size_t)(cw0 + 8 + quad) * DD + ((l15 ^ (8 + quad)) * 8);
    const unsigned short* g3 = Zib + (size_t)(cw0 + 12 + quad) * DD + ((l15 ^ (12 + quad)) * 8);

#define STG(g) do {                                                         \
        unsigned short* lb = wsl + ((g) & 1) * 2048;                        \
        __builtin_amdgcn_global_load_lds((const GLOBAL_AS void*)(g0 + (g) * 2048), \
                                         (LDS_AS void*)(lb + 0 * 512), 16, 0, 0);  \
        __builtin_amdgcn_global_load_lds((const GLOBAL_AS void*)(g1 + (g) * 2048), \
                                         (LDS_AS void*)(lb + 1 * 512), 16, 0, 0);  \
        __builtin_amdgcn_global_load_lds((const GLOBAL_AS void*)(g2 + (g) * 2048), \
                                         (LDS_AS void*)(lb + 2 * 512), 16, 0, 0);  \
        __builtin_amdgcn_global_load_lds((const GLOBAL_AS void*)(g3 + (g) * 2048), \
                                         (LDS_AS void*)(lb + 3 * 512), 16, 0, 0);  \
    } while (0)

    float rs[2][4];
#pragma unroll
    for (int mt = 0; mt < 2; ++mt)
#pragma unroll
        for (int r = 0; r < 4; ++r) rs[mt][r] = 0.0f;

    STG(0);
    STG(1);

    __builtin_amdgcn_s_setprio(1);
#pragma unroll
    for (int g = 0; g < NCH; ++g) {
        // chunk g retired when only chunk g+1's 4 ops may remain: vmcnt(4);
        // last chunk: drain.
        if (g < NCH - 1) asm volatile("s_waitcnt vmcnt(4)" ::: "memory");
        else             asm volatile("s_waitcnt vmcnt(0)" ::: "memory");
        const int P = (g & 1) * 2048;
        short8 b0 = *(const short8*)(rb0 + P);
        short8 b1 = *(const short8*)(rb1 + P);
        short8 b2 = *(const short8*)(rb2 + P);
        short8 b3 = *(const short8*)(rb3 + P);
        int ilg = (int)Il2[cw0 + g * 16 + l15];
        // capture b in regs before same-buffer overwrite (LDS write of
        // STG(g+2) lands via the TA->LDS path, unordered vs ds_read issue)
        asm volatile("s_waitcnt lgkmcnt(0)" ::: "memory");
        if (g + 2 < NCH) STG(g + 2);

        floatx4 zz = (floatx4){0.f, 0.f, 0.f, 0.f};
        floatx4 acc0, acc1;
        acc0 = __builtin_amdgcn_mfma_f32_16x16x32_bf16(af[0][0], b0, zz, 0, 0, 0);
        acc1 = __builtin_amdgcn_mfma_f32_16x16x32_bf16(af[1][0], b0, zz, 0, 0, 0);
        acc0 = __builtin_amdgcn_mfma_f32_16x16x32_bf16(af[0][1], b1, acc0, 0, 0, 0);
        acc1 = __builtin_amdgcn_mfma_f32_16x16x32_bf16(af[1][1], b1, acc1, 0, 0, 0);
        acc0 = __builtin_amdgcn_mfma_f32_16x16x32_bf16(af[0][2], b2, acc0, 0, 0, 0);
        acc1 = __builtin_amdgcn_mfma_f32_16x16x32_bf16(af[1][2], b2, acc1, 0, 0, 0);
        acc0 = __builtin_amdgcn_mfma_f32_16x16x32_bf16(af[0][3], b3, acc0, 0, 0, 0);
        acc1 = __builtin_amdgcn_mfma_f32_16x16x32_bf16(af[1][3], b3, acc1, 0, 0, 0);

        // EPI: e = exp(10c-10) via exp2; mask; accumulate
#pragma unroll
        for (int r = 0; r < 4; ++r) {
            float e0 = __builtin_amdgcn_exp2f(fmaf(acc0[r], L2E10, -L2E10));
            rs[0][r] += (ilg != jrv[r]) ? e0 : 0.0f;
            float e1 = __builtin_amdgcn_exp2f(fmaf(acc1[r], L2E10, -L2E10));
            rs[1][r] += (ilg != jrv[4 + r]) ? e1 : 0.0f;
        }
    }
    __builtin_amdgcn_s_setprio(0);
#undef STG

    // ---- combine: l15-reduce then LDS-atomic rowsum ----------------------
#pragma unroll
    for (int mt = 0; mt < 2; ++mt)
#pragma unroll
        for (int r = 0; r < 4; ++r) {
            float v = rs[mt][r];
            v += __shfl_xor(v, 1, 64);
            v += __shfl_xor(v, 2, 64);
            v += __shfl_xor(v, 4, 64);
            v += __shfl_xor(v, 8, 64);
            if (l15 == 0)
                atomicAdd(&rowsum[mt * 16 + quad * 4 + r], v);
        }
    __syncthreads();                          // all waves' denoms in rowsum

    // ---- in-block posfinal (verbatim math), 2 rows per wave --------------
    int idx2 = idxp[0];
    float ll = 0.0f;
#pragma unroll
    for (int t = 0; t < 2; ++t) {
        int irl = wave * 2 + t;
        int i = r0 + irl;
        int j = idx2 + i;
        float2 a  = *(const float2*)(zjs + (size_t)i * DD + lane * 2);
        float2 b2 = *(const float2*)(zis + (size_t)j * DD + lane * 2);
        float s = wave_sum(a.x * b2.x + a.y * b2.y);
        if (lane == 0) {
            float p = s * rni[j] * rnj[i] * 10.0f;
            float l = 10.0f + logf(__expf(p - 10.0f) + rowsum[irl]) - p;
            float w = wts[j];
            ll += (l * w) / w;    // faithful to reference's weighted mean
        }
    }
    if (lane == 0) part[wave] = ll;
    __syncthreads();
    if (tid == 0) {
        float sum = 0.0f;
#pragma unroll
        for (int q = 0; q < 16; ++q) sum += part[q];
        atomicAdd(out, sum * (1.0f / BB));
    }
}

// ---- launch --------------------------------------------------------------
extern "C" void kernel_launch(void* const* d_in, const int* in_sizes, int n_in,
                              void* d_out, int out_size, void* d_ws, size_t ws_size,
                              hipStream_t stream) {
    const float* zis = (const float*)d_in[0];
    const float* zjs = (const float*)d_in[1];
    const int* ilab = (const int*)d_in[2];
    const int* jlab = (const int*)d_in[3];
    const float* wts = (const float*)d_in[4];
    const int* idxp = (const int*)d_in[5];
    float* out = (float*)d_out;

    float* rni   = (float*)d_ws;
    float* rnj   = rni + BB;
    unsigned short* Zib = (unsigned short*)(rnj + BB);    // [BB][DD] bf16
    unsigned short* Zjb = Zib + (size_t)BB * DD;

    prep_kernel<<<2 * BB / 4, 256, 0, stream>>>(
        zis, zjs, Zib, Zjb, rni, rnj, out, out_size);
    fused_kernel<<<BB / RPB, 1024, 0, stream>>>(
        Zjb, Zib, ilab, jlab, zis, zjs, rni, rnj, wts, idxp, out);
}

// Round 13
// 165.339 us; speedup vs baseline: 1.5413x; 1.5154x over previous
//
#include <hip/hip_runtime.h>

// NTXentLoss, B=8192, D=128, T=0.1, idx=0. fp32 in, fp32 scalar out.
// R19: R15 + fence-free ticket fusion of posfinal. R18 killed the 1024-thr
// row-owner family (64-VGPR cap regardless of launch-bounds arg + >=512MB
// L2 restage floor). Budget: fill 42 | main ~35 | ~33 overhead, of which
// ~10us/dispatch x 3 is harness launch overhead -> drop one dispatch.
// R10's fusion failed on __threadfence (per-block buffer_wbl2 storms), NOT
// on the ticket idea. Atomics execute at the coherence point (never in
// L1): release = the pre-ticket __syncthreads (drains vmcnt -> denom adds
// at TCC); acquire = last block reads denom via atomicAdd(&denom[i],0.0f)
// (same-address RMW ordering). ZERO fences. 16 tail blocks do the 512-row
// posfinal (~4us, overlapped). Main loop/staging/swizzle = R15 verbatim.

#define BB 8192
#define DD 128
#define CP 256           // cols per block panel
#define RSL 512          // rows per block slice
#define NGR 16           // column granules per chunk (CP/16)

typedef __attribute__((ext_vector_type(8))) short short8;
typedef __attribute__((ext_vector_type(4))) float floatx4;

#define GLOBAL_AS __attribute__((address_space(1)))
#define LDS_AS    __attribute__((address_space(3)))

#define L2E10 14.4269504088896340f   // 10 * log2(e)

static __device__ __forceinline__ float wave_sum(float v) {
#pragma unroll
    for (int off = 32; off > 0; off >>= 1) v += __shfl_xor(v, off, 64);
    return v;
}

static __device__ __forceinline__ unsigned short f2bf(float f) {
    unsigned int u = __float_as_uint(f);
    return (unsigned short)((u + 0x7FFFu + ((u >> 16) & 1u)) >> 16);
}

// ---- prep: normalize rows -> bf16 + 1/norm; zero denom/out/tickets -------
__global__ __launch_bounds__(256) void prep_kernel(
    const float* __restrict__ zis, const float* __restrict__ zjs,
    unsigned short* __restrict__ Zib, unsigned short* __restrict__ Zjb,
    float* __restrict__ rni, float* __restrict__ rnj,
    float* __restrict__ denom, int* __restrict__ tickets,
    float* __restrict__ out, int nout)
{
    if (threadIdx.x < 2) denom[blockIdx.x * 2 + threadIdx.x] = 0.0f;
    if (blockIdx.x == 0 && (int)threadIdx.x < nout) out[threadIdx.x] = 0.0f;
    if (blockIdx.x == 1 && threadIdx.x < 16) tickets[threadIdx.x] = 0;

    int wave = threadIdx.x >> 6, lane = threadIdx.x & 63;
    int row = blockIdx.x * 4 + wave;
    const float* src; unsigned short* dst; float* rn; int r;
    if (row < BB) { src = zis; dst = Zib; rn = rni; r = row; }
    else          { src = zjs; dst = Zjb; rn = rnj; r = row - BB; }
    float2 u = *(const float2*)(src + (size_t)r * DD + lane * 2);
    float s = wave_sum(u.x * u.x + u.y * u.y);
    float sc = 1.0f / sqrtf(s);
    if (lane == 0) rn[r] = sc;
    ushort2 o; o.x = f2bf(u.x * sc); o.y = f2bf(u.y * sc);
    *(ushort2*)(dst + (size_t)r * DD + lane * 2) = o;
}

// ---- persistent-panel kernel + fused posfinal tail -----------------------
// LDS panel: col n (row stride 256 B), phys 16-B slot p stores logical slot
// s = p ^ (n & 15) (inverse swizzle on per-lane GLOBAL source, rule #21;
// gload_lds dest linear). Fragment read: p = (ks*4+quad) ^ l15 -> 0 bank
// conflicts measured (R13). Main body identical to R15 (absmax 0).
__global__ __launch_bounds__(512, 2) void panel_kernel(
    const unsigned short* __restrict__ Zjb,   // A: zj normalized (rows i)
    const unsigned short* __restrict__ Zib,   // B: zi normalized (cols j)
    const int* __restrict__ ilab, const int* __restrict__ jlab,
    float* __restrict__ denom, int* __restrict__ tickets,
    const float* __restrict__ zis, const float* __restrict__ zjs,
    const float* __restrict__ rni, const float* __restrict__ rnj,
    const float* __restrict__ wts, const int* __restrict__ idxp,
    float* __restrict__ out)
{
    __shared__ __align__(16) unsigned short Bp[CP * DD];      // 64 KB
    __shared__ int Il[CP];                                    // 1 KB
    __shared__ float part[8];
    __shared__ int tkt;

    int tid  = threadIdx.x;
    int lane = tid & 63, wave = tid >> 6;     // 8 waves
    int quad = lane >> 4, l15 = lane & 15;
    int c0    = blockIdx.y * CP;              // col panel (32)
    int rbase = blockIdx.x * RSL;             // row slice (16, fastest dim)

    // ---- stage panel + labels once ---------------------------------------
    {
        int nl = wave * 4 + quad;             // per-lane row within round
        int s  = l15 ^ (nl & 15);             // inverse swizzle on source
        const unsigned short* gp0 = Zib + (size_t)(c0 + nl) * DD + s * 8;
#pragma unroll
        for (int u = 0; u < 8; ++u) {
            const unsigned short* gp = gp0 + (size_t)u * 32 * DD;
            unsigned short* lp = &Bp[(u * 8 + wave) * 512];
            __builtin_amdgcn_global_load_lds((const GLOBAL_AS void*)gp,
                                             (LDS_AS void*)lp, 16, 0, 0);
        }
    }
    if (tid < CP) Il[tid] = ilab[c0 + tid];
    asm volatile("s_waitcnt vmcnt(0) lgkmcnt(0)" ::: "memory");
    __builtin_amdgcn_s_barrier();             // the ONLY main-phase barrier

    // granule-invariant swizzled LDS bases; granule g adds g*4096 B ->
    // compile-time imm offset on ds_read_b128 (max 15*4096+240 < 64K).
    const unsigned short* rb0 = &Bp[l15 * DD + (((0 * 4 + quad) ^ l15) * 8)];
    const unsigned short* rb1 = &Bp[l15 * DD + (((1 * 4 + quad) ^ l15) * 8)];
    const unsigned short* rb2 = &Bp[l15 * DD + (((2 * 4 + quad) ^ l15) * 8)];
    const unsigned short* rb3 = &Bp[l15 * DD + (((3 * 4 + quad) ^ l15) * 8)];
    const int* ilb = &Il[l15];                // + g*16 -> imm offset g*64

#define LDB(bx, g) do {                                       \
        bx[0] = *(const short8*)(rb0 + (g) * 16 * DD);        \
        bx[1] = *(const short8*)(rb1 + (g) * 16 * DD);        \
        bx[2] = *(const short8*)(rb2 + (g) * 16 * DD);        \
        bx[3] = *(const short8*)(rb3 + (g) * 16 * DD);        \
    } while (0)

#define MFMA8(bx) do {                                                          \
        floatx4 zz = (floatx4){0.f, 0.f, 0.f, 0.f};                             \
        acc[0] = __builtin_amdgcn_mfma_f32_16x16x32_bf16(af[0][0], bx[0], zz, 0, 0, 0); \
        acc[1] = __builtin_amdgcn_mfma_f32_16x16x32_bf16(af[1][0], bx[0], zz, 0, 0, 0); \
        acc[0] = __builtin_amdgcn_mfma_f32_16x16x32_bf16(af[0][1], bx[1], acc[0], 0, 0, 0); \
        acc[1] = __builtin_amdgcn_mfma_f32_16x16x32_bf16(af[1][1], bx[1], acc[1], 0, 0, 0); \
        acc[0] = __builtin_amdgcn_mfma_f32_16x16x32_bf16(af[0][2], bx[2], acc[0], 0, 0, 0); \
        acc[1] = __builtin_amdgcn_mfma_f32_16x16x32_bf16(af[1][2], bx[2], acc[1], 0, 0, 0); \
        acc[0] = __builtin_amdgcn_mfma_f32_16x16x32_bf16(af[0][3], bx[3], acc[0], 0, 0, 0); \
        acc[1] = __builtin_amdgcn_mfma_f32_16x16x32_bf16(af[1][3], bx[3], acc[1], 0, 0, 0); \
    } while (0)

#define EPI(ilc) do {                                         \
        _Pragma("unroll")                                     \
        for (int mt = 0; mt < 2; ++mt)                        \
            _Pragma("unroll")                                 \
            for (int r = 0; r < 4; ++r) {                     \
                float e = __builtin_amdgcn_exp2f(             \
                    fmaf(acc[mt][r], L2E10, -L2E10));         \
                rs[mt][r] += ((ilc) != jrv[mt * 4 + r]) ? e : 0.0f; \
            }                                                 \
    } while (0)

    // ---- 2 independent chunks of 32 A-rows per wave ----------------------
#pragma unroll
    for (int c = 0; c < 2; ++c) {
        int r0 = rbase + wave * 64 + c * 32;

        short8 af[2][4];
#pragma unroll
        for (int mt = 0; mt < 2; ++mt)
#pragma unroll
            for (int ks = 0; ks < 4; ++ks)
                af[mt][ks] = *(const short8*)(Zjb
                    + (size_t)(r0 + mt * 16 + l15) * DD + ks * 32 + quad * 8);

        int jrv[8];
#pragma unroll
        for (int mt = 0; mt < 2; ++mt)
#pragma unroll
            for (int r = 0; r < 4; ++r)
                jrv[mt * 4 + r] = jlab[r0 + mt * 16 + quad * 4 + r];

        float rs[2][4];
#pragma unroll
        for (int mt = 0; mt < 2; ++mt)
#pragma unroll
            for (int r = 0; r < 4; ++r) rs[mt][r] = 0.0f;

        floatx4 acc[2];
        short8 b0[4], b1[4];
        LDB(b0, 0);
        int iln = ilb[0];

        __builtin_amdgcn_s_setprio(1);
#pragma unroll
        for (int g = 0; g < NGR; g += 2) {
            LDB(b1, g + 1);                       // prefetch odd granule
            int il0 = iln; iln = ilb[(g + 1) * 16];
            MFMA8(b0);
            EPI(il0);
            if (g + 2 < NGR) LDB(b0, g + 2);      // prefetch next even
            int il1 = iln;
            if (g + 2 < NGR) iln = ilb[(g + 2) * 16];
            MFMA8(b1);
            EPI(il1);
        }
        __builtin_amdgcn_s_setprio(0);

        // reduce over l15 + atomics for this chunk's 32 rows (device scope,
        // execute at coherence point -- never cached in L1)
#pragma unroll
        for (int mt = 0; mt < 2; ++mt)
#pragma unroll
            for (int r = 0; r < 4; ++r) {
                float v = rs[mt][r];
                v += __shfl_xor(v, 1, 64);
                v += __shfl_xor(v, 2, 64);
                v += __shfl_xor(v, 4, 64);
                v += __shfl_xor(v, 8, 64);
                if (l15 == 0)
                    atomicAdd(&denom[r0 + mt * 16 + quad * 4 + r], v);
            }
    }
#undef LDB
#undef MFMA8
#undef EPI

    // ---- fence-free ticket: last panel-block of this row-slice finalizes -
    __syncthreads();   // all waves' denom atomics drained (vmcnt before bar)
    if (tid == 0) tkt = atomicAdd(&tickets[blockIdx.x], 1);
    __syncthreads();
    if (tkt == 31) {   // 32nd block: all denom adds for rows rbase..+511 at TCC
        int idx2 = idxp[0];
        float ll = 0.0f;
        for (int t = 0; t < RSL / (8 * 64) * 64; ++t) {   // 64 rows per wave
            int i = rbase + wave * 64 + t;
            int j = idx2 + i;
            float2 a  = *(const float2*)(zjs + (size_t)i * DD + lane * 2);
            float2 b2 = *(const float2*)(zis + (size_t)j * DD + lane * 2);
            float s = wave_sum(a.x * b2.x + a.y * b2.y);
            if (lane == 0) {
                // same-address atomic RMW: observes all 32 blocks' adds
                float d = atomicAdd(&denom[i], 0.0f);
                float p = s * rni[j] * rnj[i] * 10.0f;
                float l = 10.0f + logf(__expf(p - 10.0f) + d) - p;
                float w = wts[j];
                ll += (l * w) / w;    // faithful to reference's weighted mean
            }
        }
        if (lane == 0) part[wave] = ll;
        __syncthreads();
        if (tid == 0) {
            float sum = 0.0f;
#pragma unroll
            for (int q = 0; q < 8; ++q) sum += part[q];
            atomicAdd(out, sum * (1.0f / BB));
        }
    }
}

// ---- launch --------------------------------------------------------------
extern "C" void kernel_launch(void* const* d_in, const int* in_sizes, int n_in,
                              void* d_out, int out_size, void* d_ws, size_t ws_size,
                              hipStream_t stream) {
    const float* zis = (const float*)d_in[0];
    const float* zjs = (const float*)d_in[1];
    const int* ilab = (const int*)d_in[2];
    const int* jlab = (const int*)d_in[3];
    const float* wts = (const float*)d_in[4];
    const int* idxp = (const int*)d_in[5];
    float* out = (float*)d_out;

    float* rni   = (float*)d_ws;
    float* rnj   = rni + BB;
    float* denom = rnj + BB;
    int*   tickets = (int*)(denom + BB);                   // 16 ints (+pad)
    unsigned short* Zib = (unsigned short*)(tickets + 64); // [BB][DD] bf16
    unsigned short* Zjb = Zib + (size_t)BB * DD;

    prep_kernel<<<2 * BB / 4, 256, 0, stream>>>(
        zis, zjs, Zib, Zjb, rni, rnj, denom, tickets, out, out_size);
    panel_kernel<<<dim3(BB / RSL, BB / CP), 512, 0, stream>>>(
        Zjb, Zib, ilab, jlab, denom, tickets,
        zis, zjs, rni, rnj, wts, idxp, out);
}

// Round 14
// 103.056 us; speedup vs baseline: 2.4728x; 1.6044x over previous
//
#include <hip/hip_runtime.h>

// NTXentLoss, B=8192, D=128, T=0.1, idx=0. fp32 in, fp32 scalar out.
// R20: parallelize R19's tail. R19 fused correctly (absmax 0, VGPR 120,
// no fences) but the 16 tail blocks each walked 64 rows/wave SERIALLY
// (dependent load->wave_sum->atomic->logf chains, ~2K cyc/row) -> ~60us,
// occupancy 7.8%. Fix: (1) pos raw-dot rd[i] = dot(zjs[i], zis[idx+i])
// relocated to prep (zjs row already in regs there; bit-identical since
// posfinal always used raw dots x rni x rnj); (2) tail = 512 threads x 1
// row each, pure scalar lane-parallel math (~3us). Main loop, staging,
// swizzle, fence-free ticket protocol: R19 verbatim.

#define BB 8192
#define DD 128
#define CP 256           // cols per block panel
#define RSL 512          // rows per block slice
#define NGR 16           // column granules per chunk (CP/16)

typedef __attribute__((ext_vector_type(8))) short short8;
typedef __attribute__((ext_vector_type(4))) float floatx4;

#define GLOBAL_AS __attribute__((address_space(1)))
#define LDS_AS    __attribute__((address_space(3)))

#define L2E10 14.4269504088896340f   // 10 * log2(e)

static __device__ __forceinline__ float wave_sum(float v) {
#pragma unroll
    for (int off = 32; off > 0; off >>= 1) v += __shfl_xor(v, off, 64);
    return v;
}

static __device__ __forceinline__ unsigned short f2bf(float f) {
    unsigned int u = __float_as_uint(f);
    return (unsigned short)((u + 0x7FFFu + ((u >> 16) & 1u)) >> 16);
}

// ---- prep: normalize rows -> bf16 + 1/norm; raw pos-dot; zero bufs -------
__global__ __launch_bounds__(256) void prep_kernel(
    const float* __restrict__ zis, const float* __restrict__ zjs,
    unsigned short* __restrict__ Zib, unsigned short* __restrict__ Zjb,
    float* __restrict__ rni, float* __restrict__ rnj,
    float* __restrict__ rd, const int* __restrict__ idxp,
    float* __restrict__ denom, int* __restrict__ tickets,
    float* __restrict__ out, int nout)
{
    if (threadIdx.x < 2) denom[blockIdx.x * 2 + threadIdx.x] = 0.0f;
    if (blockIdx.x == 0 && (int)threadIdx.x < nout) out[threadIdx.x] = 0.0f;
    if (blockIdx.x == 1 && threadIdx.x < 16) tickets[threadIdx.x] = 0;

    int wave = threadIdx.x >> 6, lane = threadIdx.x & 63;
    int row = blockIdx.x * 4 + wave;
    const float* src; unsigned short* dst; float* rn; int r; int isj;
    if (row < BB) { src = zis; dst = Zib; rn = rni; r = row; isj = 0; }
    else          { src = zjs; dst = Zjb; rn = rnj; r = row - BB; isj = 1; }
    float2 u = *(const float2*)(src + (size_t)r * DD + lane * 2);
    float s = wave_sum(u.x * u.x + u.y * u.y);
    float sc = 1.0f / sqrtf(s);
    if (lane == 0) rn[r] = sc;
    ushort2 o; o.x = f2bf(u.x * sc); o.y = f2bf(u.y * sc);
    *(ushort2*)(dst + (size_t)r * DD + lane * 2) = o;

    // raw pos-dot for loss row r (zjs waves only): rd[r] = zjs[r].zis[idx+r]
    // (posfinal always used RAW dots, scaled later by rni*rnj -> bit-same)
    if (isj) {
        int j = idxp[0] + r;
        float2 b2 = *(const float2*)(zis + (size_t)j * DD + lane * 2);
        float d = wave_sum(u.x * b2.x + u.y * b2.y);
        if (lane == 0) rd[r] = d;
    }
}

// ---- persistent-panel kernel + lane-parallel fused posfinal tail ---------
// LDS panel: col n (row stride 256 B), phys 16-B slot p stores logical slot
// s = p ^ (n & 15) (inverse swizzle on per-lane GLOBAL source, rule #21;
// gload_lds dest linear). Fragment read: p = (ks*4+quad) ^ l15 -> 0 bank
// conflicts measured (R13). Main body identical to R15/R19 (absmax 0).
__global__ __launch_bounds__(512, 2) void panel_kernel(
    const unsigned short* __restrict__ Zjb,   // A: zj normalized (rows i)
    const unsigned short* __restrict__ Zib,   // B: zi normalized (cols j)
    const int* __restrict__ ilab, const int* __restrict__ jlab,
    float* __restrict__ denom, int* __restrict__ tickets,
    const float* __restrict__ rd,
    const float* __restrict__ rni, const float* __restrict__ rnj,
    const float* __restrict__ wts, const int* __restrict__ idxp,
    float* __restrict__ out)
{
    __shared__ __align__(16) unsigned short Bp[CP * DD];      // 64 KB
    __shared__ int Il[CP];                                    // 1 KB
    __shared__ float part[8];
    __shared__ int tkt;

    int tid  = threadIdx.x;
    int lane = tid & 63, wave = tid >> 6;     // 8 waves
    int quad = lane >> 4, l15 = lane & 15;
    int c0    = blockIdx.y * CP;              // col panel (32)
    int rbase = blockIdx.x * RSL;             // row slice (16, fastest dim)

    // ---- stage panel + labels once ---------------------------------------
    {
        int nl = wave * 4 + quad;             // per-lane row within round
        int s  = l15 ^ (nl & 15);             // inverse swizzle on source
        const unsigned short* gp0 = Zib + (size_t)(c0 + nl) * DD + s * 8;
#pragma unroll
        for (int u = 0; u < 8; ++u) {
            const unsigned short* gp = gp0 + (size_t)u * 32 * DD;
            unsigned short* lp = &Bp[(u * 8 + wave) * 512];
            __builtin_amdgcn_global_load_lds((const GLOBAL_AS void*)gp,
                                             (LDS_AS void*)lp, 16, 0, 0);
        }
    }
    if (tid < CP) Il[tid] = ilab[c0 + tid];
    asm volatile("s_waitcnt vmcnt(0) lgkmcnt(0)" ::: "memory");
    __builtin_amdgcn_s_barrier();             // the ONLY main-phase barrier

    // granule-invariant swizzled LDS bases; granule g adds g*4096 B ->
    // compile-time imm offset on ds_read_b128 (max 15*4096+240 < 64K).
    const unsigned short* rb0 = &Bp[l15 * DD + (((0 * 4 + quad) ^ l15) * 8)];
    const unsigned short* rb1 = &Bp[l15 * DD + (((1 * 4 + quad) ^ l15) * 8)];
    const unsigned short* rb2 = &Bp[l15 * DD + (((2 * 4 + quad) ^ l15) * 8)];
    const unsigned short* rb3 = &Bp[l15 * DD + (((3 * 4 + quad) ^ l15) * 8)];
    const int* ilb = &Il[l15];                // + g*16 -> imm offset g*64

#define LDB(bx, g) do {                                       \
        bx[0] = *(const short8*)(rb0 + (g) * 16 * DD);        \
        bx[1] = *(const short8*)(rb1 + (g) * 16 * DD);        \
        bx[2] = *(const short8*)(rb2 + (g) * 16 * DD);        \
        bx[3] = *(const short8*)(rb3 + (g) * 16 * DD);        \
    } while (0)

#define MFMA8(bx) do {                                                          \
        floatx4 zz = (floatx4){0.f, 0.f, 0.f, 0.f};                             \
        acc[0] = __builtin_amdgcn_mfma_f32_16x16x32_bf16(af[0][0], bx[0], zz, 0, 0, 0); \
        acc[1] = __builtin_amdgcn_mfma_f32_16x16x32_bf16(af[1][0], bx[0], zz, 0, 0, 0); \
        acc[0] = __builtin_amdgcn_mfma_f32_16x16x32_bf16(af[0][1], bx[1], acc[0], 0, 0, 0); \
        acc[1] = __builtin_amdgcn_mfma_f32_16x16x32_bf16(af[1][1], bx[1], acc[1], 0, 0, 0); \
        acc[0] = __builtin_amdgcn_mfma_f32_16x16x32_bf16(af[0][2], bx[2], acc[0], 0, 0, 0); \
        acc[1] = __builtin_amdgcn_mfma_f32_16x16x32_bf16(af[1][2], bx[2], acc[1], 0, 0, 0); \
        acc[0] = __builtin_amdgcn_mfma_f32_16x16x32_bf16(af[0][3], bx[3], acc[0], 0, 0, 0); \
        acc[1] = __builtin_amdgcn_mfma_f32_16x16x32_bf16(af[1][3], bx[3], acc[1], 0, 0, 0); \
    } while (0)

#define EPI(ilc) do {                                         \
        _Pragma("unroll")                                     \
        for (int mt = 0; mt < 2; ++mt)                        \
            _Pragma("unroll")                                 \
            for (int r = 0; r < 4; ++r) {                     \
                float e = __builtin_amdgcn_exp2f(             \
                    fmaf(acc[mt][r], L2E10, -L2E10));         \
                rs[mt][r] += ((ilc) != jrv[mt * 4 + r]) ? e : 0.0f; \
            }                                                 \
    } while (0)

    // ---- 2 independent chunks of 32 A-rows per wave ----------------------
#pragma unroll
    for (int c = 0; c < 2; ++c) {
        int r0 = rbase + wave * 64 + c * 32;

        short8 af[2][4];
#pragma unroll
        for (int mt = 0; mt < 2; ++mt)
#pragma unroll
            for (int ks = 0; ks < 4; ++ks)
                af[mt][ks] = *(const short8*)(Zjb
                    + (size_t)(r0 + mt * 16 + l15) * DD + ks * 32 + quad * 8);

        int jrv[8];
#pragma unroll
        for (int mt = 0; mt < 2; ++mt)
#pragma unroll
            for (int r = 0; r < 4; ++r)
                jrv[mt * 4 + r] = jlab[r0 + mt * 16 + quad * 4 + r];

        float rs[2][4];
#pragma unroll
        for (int mt = 0; mt < 2; ++mt)
#pragma unroll
            for (int r = 0; r < 4; ++r) rs[mt][r] = 0.0f;

        floatx4 acc[2];
        short8 b0[4], b1[4];
        LDB(b0, 0);
        int iln = ilb[0];

        __builtin_amdgcn_s_setprio(1);
#pragma unroll
        for (int g = 0; g < NGR; g += 2) {
            LDB(b1, g + 1);                       // prefetch odd granule
            int il0 = iln; iln = ilb[(g + 1) * 16];
            MFMA8(b0);
            EPI(il0);
            if (g + 2 < NGR) LDB(b0, g + 2);      // prefetch next even
            int il1 = iln;
            if (g + 2 < NGR) iln = ilb[(g + 2) * 16];
            MFMA8(b1);
            EPI(il1);
        }
        __builtin_amdgcn_s_setprio(0);

        // reduce over l15 + atomics for this chunk's 32 rows (device scope,
        // execute at coherence point -- never cached in L1)
#pragma unroll
        for (int mt = 0; mt < 2; ++mt)
#pragma unroll
            for (int r = 0; r < 4; ++r) {
                float v = rs[mt][r];
                v += __shfl_xor(v, 1, 64);
                v += __shfl_xor(v, 2, 64);
                v += __shfl_xor(v, 4, 64);
                v += __shfl_xor(v, 8, 64);
                if (l15 == 0)
                    atomicAdd(&denom[r0 + mt * 16 + quad * 4 + r], v);
            }
    }
#undef LDB
#undef MFMA8
#undef EPI

    // ---- fence-free ticket: last panel-block of this row-slice finalizes -
    __syncthreads();   // all waves' denom atomics drained (vmcnt before bar)
    if (tid == 0) tkt = atomicAdd(&tickets[blockIdx.x], 1);
    __syncthreads();
    if (tkt == 31) {   // 32nd block: all denom adds for rows rbase..+511 at TCC
        // lane-parallel: 512 threads x 1 row each; pure scalar chain.
        int idx2 = idxp[0];
        int i = rbase + tid;
        int j = idx2 + i;
        // same-address atomic RMW: observes all 32 blocks' prior adds
        float d = atomicAdd(&denom[i], 0.0f);
        float p = rd[i] * rni[j] * rnj[i] * 10.0f;
        float l = 10.0f + logf(__expf(p - 10.0f) + d) - p;
        float w = wts[j];
        float ll = (l * w) / w;       // faithful to reference's weighted mean
        ll = wave_sum(ll);
        if (lane == 0) part[wave] = ll;
        __syncthreads();
        if (tid == 0) {
            float sum = 0.0f;
#pragma unroll
            for (int q = 0; q < 8; ++q) sum += part[q];
            atomicAdd(out, sum * (1.0f / BB));
        }
    }
}

// ---- launch --------------------------------------------------------------
extern "C" void kernel_launch(void* const* d_in, const int* in_sizes, int n_in,
                              void* d_out, int out_size, void* d_ws, size_t ws_size,
                              hipStream_t stream) {
    const float* zis = (const float*)d_in[0];
    const float* zjs = (const float*)d_in[1];
    const int* ilab = (const int*)d_in[2];
    const int* jlab = (const int*)d_in[3];
    const float* wts = (const float*)d_in[4];
    const int* idxp = (const int*)d_in[5];
    float* out = (float*)d_out;

    float* rni   = (float*)d_ws;
    float* rnj   = rni + BB;
    float* denom = rnj + BB;
    float* rd    = denom + BB;                             // raw pos-dots
    int*   tickets = (int*)(rd + BB);                      // 16 ints (+pad)
    unsigned short* Zib = (unsigned short*)(tickets + 64); // [BB][DD] bf16
    unsigned short* Zjb = Zib + (size_t)BB * DD;

    prep_kernel<<<2 * BB / 4, 256, 0, stream>>>(
        zis, zjs, Zib, Zjb, rni, rnj, rd, idxp, denom, tickets, out, out_size);
    panel_kernel<<<dim3(BB / RSL, BB / CP), 512, 0, stream>>>(
        Zjb, Zib, ilab, jlab, denom, tickets,
        rd, rni, rnj, wts, idxp, out);
}